// Round 12
// baseline (159.123 us; speedup 1.0000x reference)
//
#include <hip/hip_runtime.h>
#include <math.h>

typedef __attribute__((ext_vector_type(4))) int i32x4;
typedef __attribute__((ext_vector_type(16))) int i32x16;
typedef signed char s8;

constexpr int S   = 2048;
constexpr int HID = 2048;
constexpr int NH  = 16;
constexpr int HD  = 128;
constexpr int HALF = 64;

#define SCORE_SCALE ((float)(0.06 * 0.06 * 0.08838834764831845))   // Q_ROT*K_ROT*INV_SQRT_HD
#define OSCALE      ((float)(((1.0 / 127.0) * 0.04) / 0.03))        // PROB*V_OUT/OUT_IN

__device__ __forceinline__ float clip127(float r){
  return fminf(fmaxf(r, -127.0f), 127.0f);
}
__device__ __forceinline__ i32x4 mfma_i8(i32x4 a, i32x4 b, i32x4 c){
  return __builtin_amdgcn_mfma_i32_16x16x64_i8(a, b, c, 0, 0, 0);
}
// async 16B global -> LDS (direct-to-LDS DMA, no VGPR round trip)
__device__ __forceinline__ void async16(const void* g, void* l){
  __builtin_amdgcn_global_load_lds(
      (const __attribute__((address_space(1))) unsigned*)g,
      (__attribute__((address_space(3))) unsigned*)l, 16, 0, 0);
}
// Stage ROWSx128 int8 tile: linear LDS dest (lane-ordered), inverse-swizzled
// global source, so swizzled reads (rd16) return the right data. [m173 pattern]
template<int ROWS>
__device__ __forceinline__ void stage_async_swz(s8* dst, const s8* src, int stride){
  const int tid = threadIdx.x;
#pragma unroll
  for (int i = 0; i < ROWS/32; ++i){
    int o = i*256 + tid;                 // 16B-chunk index (256 threads)
    int row = o >> 3, ch = o & 7;
    async16(src + (size_t)row*stride + ((ch ^ (row & 7))*16), dst + o*16);
  }
}
// same, for 128-thread blocks
__device__ __forceinline__ void stage_tile_128thr(s8* dst, const s8* src, int stride){
  const int tid = threadIdx.x;
#pragma unroll
  for (int i = 0; i < 8; ++i){
    int o = i*128 + tid;
    int row = o >> 3, ch = o & 7;
    async16(src + (size_t)row*stride + ((ch ^ (row & 7))*16), dst + o*16);
  }
}
__device__ __forceinline__ i32x4 rd16(const s8* buf, int row, int ch){
  return *(const i32x4*)(buf + row*128 + ((ch ^ (row & 7))*16));
}
// decode triangular index t -> qt (t = qt*(qt+1)/2 + kt)
__device__ __forceinline__ int tri_qt(int t){
  int qt = (int)((sqrtf(8.f*t + 1.f) - 1.f)*0.5f);
  while ((qt+1)*(qt+2)/2 <= t) ++qt;
  while (qt*(qt+1)/2 > t) --qt;
  return qt;
}

// ---------------- prep: one dispatch converts x (quant) + 4 weights -> int8 ----
__global__ void cvt_all(const float* __restrict__ hid, const float* __restrict__ wq,
                        const float* __restrict__ wk, const float* __restrict__ wv,
                        const float* __restrict__ wo, s8* __restrict__ xd,
                        s8* __restrict__ qd, s8* __restrict__ kd,
                        s8* __restrict__ vd, s8* __restrict__ od, int n){
  const float* srcs[5] = {hid, wq, wk, wv, wo};
  s8* dsts[5] = {xd, qd, kd, vd, od};
  int which = blockIdx.y;
  const float* src = srcs[which];
  s8* dst = dsts[which];
  int i = (blockIdx.x * blockDim.x + threadIdx.x) * 4;
  if (i >= n) return;
  float4 v = *(const float4*)(src + i);
  float x[4] = {v.x, v.y, v.z, v.w};
  unsigned packed = 0;
#pragma unroll
  for (int j = 0; j < 4; ++j){
    int b;
    if (which == 0) b = (int)clip127(rintf(x[j] / 0.02f));
    else            b = (int)x[j];
    packed |= ((unsigned)(b & 255)) << (8*j);
  }
  *(unsigned*)(dst + i) = packed;
}

// ---------------- fused QKV GEMM: 128x128 tile, 32x32x32 i8 MFMA ---------------
// grid (16,16,3), 128 threads (2 waves). Wave w owns rows w*64..+64 x 128 cols
// as 2x4 fragments of 32x32 -> 42.7 MAC per LDS byte (vs 32 for 16x16 shape).
// A/B frag: lane l -> row/col (l&31), K-chunk (l>>5). C/D: col=lane&31,
// row=(r&3)+8*(r>>2)+4*(lane>>5) [m74/m101, dtype-independent m121-128].
__global__ __launch_bounds__(128)
void gemm_qkv(const s8* __restrict__ A, const s8* __restrict__ W,
              const float* __restrict__ bq, const float* __restrict__ bk,
              const float* __restrict__ bv, s8* __restrict__ Out){
#pragma clang fp contract(off)
  constexpr int Kd = 2048, N = 2048;
  const int z = blockIdx.z;
  const s8* Bt = W + (size_t)z*(4u<<20);
  s8* Y = Out + (size_t)z*(4u<<20);
  const float* bss[3] = {bq, bk, bv};
  const float* bias = bss[z];
  __shared__ __attribute__((aligned(16))) s8 As[128*128];
  __shared__ __attribute__((aligned(16))) s8 Bs[128*128];
  const int bm = blockIdx.x, bn = blockIdx.y, tid = threadIdx.x;
  const int wid = tid >> 6, lane = tid & 63;
  const int l31 = lane & 31, hi = lane >> 5;
  i32x16 acc[2][4] = {};
  const s8* Ab = A + (size_t)(bm*128)*Kd;
  const s8* Bb = Bt + (size_t)(bn*128)*Kd;
  for (int kt = 0; kt < 16; ++kt){
    stage_tile_128thr(As, Ab + kt*128, Kd);
    stage_tile_128thr(Bs, Bb + kt*128, Kd);
    __syncthreads();                       // drains vmcnt -> LDS ready
#pragma unroll
    for (int kk = 0; kk < 4; ++kk){        // K-chunks of 32
      const int ch = kk*2 + hi;
      i32x4 af[2], bf[4];
#pragma unroll
      for (int i = 0; i < 2; ++i) af[i] = rd16(As, wid*64 + i*32 + l31, ch);
#pragma unroll
      for (int j = 0; j < 4; ++j) bf[j] = rd16(Bs, j*32 + l31, ch);
#pragma unroll
      for (int i = 0; i < 2; ++i)
#pragma unroll
        for (int j = 0; j < 4; ++j)
          acc[i][j] = __builtin_amdgcn_mfma_i32_32x32x32_i8(af[i], bf[j], acc[i][j], 0, 0, 0);
    }
    __syncthreads();                       // all reads retired before restage
  }
#pragma unroll
  for (int i = 0; i < 2; ++i){
#pragma unroll
    for (int j = 0; j < 4; ++j){
      int col = bn*128 + j*32 + l31;
      float b = bias[col];
#pragma unroll
      for (int r = 0; r < 16; ++r){
        int row = bm*128 + wid*64 + i*32 + (r & 3) + 8*(r >> 2) + 4*hi;
        float t = (float)acc[i][j][r] * 0.002f;
        t = t + b;
        Y[(size_t)row*N + col] = (s8)(int)clip127(rintf(t));
      }
    }
  }
}

// ---------------- O-projection GEMM: 128x64 tile, single-buffer ----------------
__global__ __launch_bounds__(256)
void gemm_o(const s8* __restrict__ A, const s8* __restrict__ Bt,
            const float* __restrict__ bias, float* __restrict__ Y){
#pragma clang fp contract(off)
  constexpr int Kd = 2048, N = 2048;
  __shared__ __attribute__((aligned(16))) s8 As[128*128];
  __shared__ __attribute__((aligned(16))) s8 Bs[64*128];
  const int bm = blockIdx.x, bn = blockIdx.y, tid = threadIdx.x;
  const int wid = tid >> 6, lane = tid & 63;
  const int wm = wid >> 1, wn = wid & 1;     // 2x2 waves -> 64x32 subtiles
  const int col16 = lane & 15, g = lane >> 4;
  i32x4 acc[4][2] = {};
  const s8* Ab = A + (size_t)(bm*128)*Kd;
  const s8* Bb = Bt + (size_t)(bn*64)*Kd;
  for (int kt = 0; kt < 16; ++kt){
    stage_async_swz<128>(As, Ab + kt*128, Kd);
    stage_async_swz<64>(Bs, Bb + kt*128, Kd);
    __syncthreads();
#pragma unroll
    for (int kk = 0; kk < 2; ++kk){
      i32x4 af[4], bf[2];
#pragma unroll
      for (int i = 0; i < 4; ++i) af[i] = rd16(As, wm*64 + i*16 + col16, kk*4 + g);
#pragma unroll
      for (int j = 0; j < 2; ++j) bf[j] = rd16(Bs, wn*32 + j*16 + col16, kk*4 + g);
#pragma unroll
      for (int i = 0; i < 4; ++i)
#pragma unroll
        for (int j = 0; j < 2; ++j)
          acc[i][j] = mfma_i8(af[i], bf[j], acc[i][j]);
    }
    __syncthreads();
  }
#pragma unroll
  for (int i = 0; i < 4; ++i){
#pragma unroll
    for (int j = 0; j < 2; ++j){
      int row0 = bm*128 + wm*64 + i*16 + g*4;
      int col  = bn*64 + wn*32 + j*16 + col16;
#pragma unroll
      for (int r = 0; r < 4; ++r){
        float t = (float)acc[i][j][r] * 0.001f;
        t = t + bias[col];
        Y[(size_t)(row0 + r)*N + col] = t;
      }
    }
  }
}

// ---------------- RoPE (in place on int8 q/k) ----------------------------------
__global__ void rope_qk(s8* __restrict__ q, s8* __restrict__ k,
                        const float* __restrict__ cosp, const float* __restrict__ sinp){
#pragma clang fp contract(off)
  int idx = blockIdx.x * blockDim.x + threadIdx.x;   // S*NH*16 threads
  int t4 = (idx & 15) * 4;
  int h  = (idx >> 4) & (NH-1);
  int s  = idx >> 8;
  if (s >= S) return;
  float4 c4 = *(const float4*)(cosp + s*HALF + t4);
  float4 s4 = *(const float4*)(sinp + s*HALF + t4);
  float cc[4] = {c4.x, c4.y, c4.z, c4.w}, ss[4] = {s4.x, s4.y, s4.z, s4.w};
  int base = s*HID + h*HD + t4;
  {
    int a0 = *(const int*)(q + base), a1 = *(const int*)(q + base + HALF);
    unsigned o0 = 0, o1 = 0;
#pragma unroll
    for (int j = 0; j < 4; ++j){
      float x0 = (float)((s8)(a0 >> (8*j))) * 0.05f;
      float x1 = (float)((s8)(a1 >> (8*j))) * 0.05f;
      float r0 = x0*cc[j] - x1*ss[j];
      float r1 = x0*ss[j] + x1*cc[j];
      o0 |= ((unsigned)(((int)clip127(rintf(r0 / 0.06f))) & 255)) << (8*j);
      o1 |= ((unsigned)(((int)clip127(rintf(r1 / 0.06f))) & 255)) << (8*j);
    }
    *(unsigned*)(q + base) = o0; *(unsigned*)(q + base + HALF) = o1;
  }
  {
    int a0 = *(const int*)(k + base), a1 = *(const int*)(k + base + HALF);
    unsigned o0 = 0, o1 = 0;
#pragma unroll
    for (int j = 0; j < 4; ++j){
      float x0 = (float)((s8)(a0 >> (8*j))) * 0.05f;
      float x1 = (float)((s8)(a1 >> (8*j))) * 0.05f;
      float r0 = x0*cc[j] - x1*ss[j];
      float r1 = x0*ss[j] + x1*cc[j];
      o0 |= ((unsigned)(((int)clip127(rintf(r0 / 0.06f))) & 255)) << (8*j);
      o1 |= ((unsigned)(((int)clip127(rintf(r1 / 0.06f))) & 255)) << (8*j);
    }
    *(unsigned*)(k + base) = o0; *(unsigned*)(k + base + HALF) = o1;
  }
}

// ---------------- V transpose (int8): vt[h][d][s] = v[s][h*HD+d] ---------------
__global__ void vtrans(const s8* __restrict__ v, s8* __restrict__ vt){
  __shared__ __attribute__((aligned(16))) s8 t[128*144];
  int s0 = blockIdx.x * 128, h = blockIdx.y;
  int tid = threadIdx.x;
#pragma unroll
  for (int i = 0; i < 4; ++i){
    int vv = i*256 + tid, r = vv >> 3, ch = vv & 7;
    *(i32x4*)(t + r*144 + ch*16) = *(const i32x4*)(v + (size_t)(s0 + r)*HID + h*HD + ch*16);
  }
  __syncthreads();
#pragma unroll
  for (int i = 0; i < 4; ++i){
    int vv = i*256 + tid, d = vv >> 3, sc = (vv & 7)*16;
    s8 tmp[16];
#pragma unroll
    for (int j = 0; j < 16; ++j) tmp[j] = t[(sc + j)*144 + d];
    *(i32x4*)(vt + (size_t)(h*HD + d)*S + s0 + sc) = *(i32x4*)tmp;
  }
}

// ---------------- S: tile stats at 64-row half-tile granularity ----------------
// grid (272,16): x -> (tri = x>>1, half = x&1). i32-domain max (bit-exact).
__global__ __launch_bounds__(256)
void attn_stats(const s8* __restrict__ qr, const s8* __restrict__ kr,
                float2* __restrict__ stats){
  const int x = blockIdx.x, h = blockIdx.y;
  const int tri = x >> 1, half = x & 1;
  const int qt = tri_qt(tri);
  const int kt = tri - qt*(qt+1)/2;
  const int q0 = qt*128 + half*64;
  const int tid = threadIdx.x, wid = tid >> 6, lane = tid & 63;
  const int col16 = lane & 15, g = lane >> 4;
  __shared__ __attribute__((aligned(16))) s8 Ks[128*128];

  stage_async_swz<128>(Ks, kr + (size_t)(kt*128)*HID + h*HD, HID);
  const s8* qb = qr + (size_t)(q0 + wid*16 + col16)*HID + h*HD + g*16;
  i32x4 aq[2];
  aq[0] = *(const i32x4*)(qb);
  aq[1] = *(const i32x4*)(qb + 64);
  __syncthreads();

  i32x4 sc[8] = {};
#pragma unroll
  for (int kk = 0; kk < 2; ++kk){
#pragma unroll
    for (int j = 0; j < 8; ++j){
      i32x4 bk = rd16(Ks, j*16 + col16, kk*4 + g);
      sc[j] = mfma_i8(aq[kk], bk, sc[j]);
    }
  }

  const bool diag = (kt == qt);
#pragma unroll
  for (int r = 0; r < 4; ++r){
    int rit = half*64 + wid*16 + g*4 + r;
    int qrow = qt*128 + rit;
    int mi = (int)0x80000000;
#pragma unroll
    for (int j = 0; j < 8; ++j){
      int v = sc[j][r];
      if (diag && (kt*128 + j*16 + col16 > qrow)) v = (int)0x80000000;
      mi = max(mi, v);
    }
    mi = max(mi, __shfl_xor(mi, 1));
    mi = max(mi, __shfl_xor(mi, 2));
    mi = max(mi, __shfl_xor(mi, 4));
    mi = max(mi, __shfl_xor(mi, 8));
    float mf = (float)mi * SCORE_SCALE;    // == f32 max (monotone map, exact cvt)
    float st = 0.f;
#pragma unroll
    for (int j = 0; j < 8; ++j){
      float arg;
      if (diag && (kt*128 + j*16 + col16 > qrow)) arg = -1e30f;  // exp -> 0.0f
      else arg = (float)sc[j][r] * SCORE_SCALE - mf;
      st += __expf(arg);
    }
    st += __shfl_xor(st, 1);
    st += __shfl_xor(st, 2);
    st += __shfl_xor(st, 4);
    st += __shfl_xor(st, 8);
    if (col16 == 0) stats[(size_t)(h*136 + tri)*128 + rit] = make_float2(mf, st);
  }
}

// ---------------- R: combine tile stats -> final (m, l) per row ----------------
__global__ void attn_reduce(const float2* __restrict__ stats, float2* __restrict__ ml){
  const int row = threadIdx.x, qt = blockIdx.x, h = blockIdx.y;
  const int tri = qt*(qt+1)/2;
  float m = -3.0e38f;
  for (int kt = 0; kt <= qt; ++kt)
    m = fmaxf(m, stats[(size_t)(h*136 + tri + kt)*128 + row].x);
  float l = 0.f;
  for (int kt = 0; kt <= qt; ++kt){
    float2 s = stats[(size_t)(h*136 + tri + kt)*128 + row];
    l += s.y * __expf(s.x - m);
  }
  ml[(h*16 + qt)*128 + row] = make_float2(m, l);
}

// ---------------- Q: p8 half-tile -> global P8 (j-serial, low VGPR) ------------
__global__ __launch_bounds__(256)
void attn_score(const s8* __restrict__ qr, const s8* __restrict__ kr,
                const float2* __restrict__ ml, s8* __restrict__ P8){
  const int x = blockIdx.x, h = blockIdx.y;
  const int tri = x >> 1, half = x & 1;
  const int qt = tri_qt(tri);
  const int kt = tri - qt*(qt+1)/2;
  const int q0 = qt*128 + half*64;
  const int tid = threadIdx.x, wid = tid >> 6, lane = tid & 63;
  const int col16 = lane & 15, g = lane >> 4;
  __shared__ __attribute__((aligned(16))) s8 Ks[128*128];
  __shared__ __attribute__((aligned(16))) s8 Pl[64*128];

  stage_async_swz<128>(Ks, kr + (size_t)(kt*128)*HID + h*HD, HID);
  const s8* qb = qr + (size_t)(q0 + wid*16 + col16)*HID + h*HD + g*16;
  i32x4 aq[2];
  aq[0] = *(const i32x4*)(qb);
  aq[1] = *(const i32x4*)(qb + 64);
  float m[4], c[4];
#pragma unroll
  for (int r = 0; r < 4; ++r){
    float2 t = ml[(h*16 + qt)*128 + half*64 + wid*16 + g*4 + r];
    m[r] = t.x;
    c[r] = 127.0f / t.y;
  }
  __syncthreads();

  const bool diag = (kt == qt);
#pragma unroll
  for (int j = 0; j < 8; ++j){
    i32x4 s0 = {};
    s0 = mfma_i8(aq[0], rd16(Ks, j*16 + col16, g), s0);
    s0 = mfma_i8(aq[1], rd16(Ks, j*16 + col16, 4 + g), s0);
    int colk = j*16 + col16;
#pragma unroll
    for (int r = 0; r < 4; ++r){
      int row = wid*16 + g*4 + r;          // local row in [0,64)
      int qrow = q0 + row;
      float p8v = 0.0f;
      if (!diag || (kt*128 + colk) <= qrow){
        float sv = (float)s0[r] * SCORE_SCALE;
        p8v = clip127(rintf(__expf(sv - m[r]) * c[r]));
      }
      Pl[row*128 + colk] = (s8)(int)p8v;
    }
  }
  __syncthreads();
  s8* dst = P8 + (size_t)(h*136 + tri)*16384 + half*8192;
#pragma unroll
  for (int i = 0; i < 2; ++i){
    int o = i*256 + tid;
    *(i32x4*)(dst + o*16) = *(const i32x4*)(Pl + o*16);
  }
}

// ---------------- P: PV — LDS-staged (gemm-identical structure), d-half split --
// grid (16,16,2): x -> qt = 15-x (deepest blocks launch first), z = d-half.
// Per kt-tile: async-stage P(16KB)+V(8KB) -> barrier -> 16 MFMA/wave -> barrier.
__global__ __launch_bounds__(256)
void attn_pv(const s8* __restrict__ P8, const s8* __restrict__ vt8,
             s8* __restrict__ o8){
  const int qt = 15 - blockIdx.x;          // deepest first
  const int h = blockIdx.y, dh = blockIdx.z;
  const int tri = qt*(qt+1)/2;
  const int tid = threadIdx.x, wid = tid >> 6, lane = tid & 63;
  const int wm = wid >> 1, wn = wid & 1;   // 2x2 waves: 64 rows x 32 d each
  const int col16 = lane & 15, g = lane >> 4;
  __shared__ __attribute__((aligned(16))) s8 Ps[128*128];
  __shared__ __attribute__((aligned(16))) s8 Vs[64*128];

  i32x4 acc[4][2] = {};
  for (int kt = 0; kt <= qt; ++kt){
    stage_async_swz<128>(Ps, P8 + (size_t)(h*136 + tri + kt)*16384, 128);
    stage_async_swz<64>(Vs, vt8 + (size_t)(h*HD + dh*64)*S + kt*128, S);
    __syncthreads();                       // drains vmcnt -> LDS ready
#pragma unroll
    for (int kk = 0; kk < 2; ++kk){
      i32x4 af[4], bf[2];
#pragma unroll
      for (int i = 0; i < 4; ++i) af[i] = rd16(Ps, wm*64 + i*16 + col16, kk*4 + g);
#pragma unroll
      for (int j = 0; j < 2; ++j) bf[j] = rd16(Vs, wn*32 + j*16 + col16, kk*4 + g);
#pragma unroll
      for (int i = 0; i < 4; ++i)
#pragma unroll
        for (int j = 0; j < 2; ++j)
          acc[i][j] = mfma_i8(af[i], bf[j], acc[i][j]);
    }
    __syncthreads();                       // all reads retired before restage
  }
#pragma unroll
  for (int i = 0; i < 4; ++i)
#pragma unroll
    for (int j = 0; j < 2; ++j)
#pragma unroll
      for (int r = 0; r < 4; ++r){
        int row = qt*128 + wm*64 + i*16 + g*4 + r;
        int d = dh*64 + wn*32 + j*16 + col16;
        o8[(size_t)row*HID + h*HD + d] = (s8)(int)clip127(rintf((float)acc[i][j][r] * OSCALE));
      }
}

// ---------------- launch --------------------------------------------------------
extern "C" void kernel_launch(void* const* d_in, const int* in_sizes, int n_in,
                              void* d_out, int out_size, void* d_ws, size_t ws_size,
                              hipStream_t stream) {
  const float* hidden = (const float*)d_in[0];
  const float* cosp   = (const float*)d_in[1];
  const float* sinp   = (const float*)d_in[2];
  const float* wq     = (const float*)d_in[3];
  const float* wk     = (const float*)d_in[4];
  const float* wv     = (const float*)d_in[5];
  const float* wo     = (const float*)d_in[6];
  const float* bq     = (const float*)d_in[7];
  const float* bk     = (const float*)d_in[8];
  const float* bv     = (const float*)d_in[9];
  const float* bo     = (const float*)d_in[10];
  float* out = (float*)d_out;

  const size_t MB = 1024*1024;
  s8* ws8 = (s8*)d_ws;
  s8* x8  = ws8 + 0*MB;     // 4MB; reused as o8 (x8 dead after QKV GEMM)
  s8* wq8 = ws8 + 4*MB;     // {wq,wk,wv} contiguous for fused QKV GEMM
  s8* wk8 = ws8 + 8*MB;
  s8* wv8 = ws8 + 12*MB;
  s8* wo8 = ws8 + 16*MB;
  s8* q8  = ws8 + 20*MB;    // {q,k,v} contiguous (gemm_qkv writes via z offset)
  s8* k8  = ws8 + 24*MB;
  s8* v8  = ws8 + 28*MB;
  s8* vt8 = ws8 + 32*MB;    // v transposed per head
  s8* P8  = ws8 + 36*MB;    // 16*136*16384 = 35.65MB -> ends ~71.7MB
  s8* o8  = x8;
  float2* stats = (float2*)(ws8 + 4*MB);                 // overlays dead wq8
  float2* mlb   = (float2*)(ws8 + 4*MB + 2400*1024);

  const int n = HID*HID;
  dim3 b256(256);

  cvt_all<<<dim3(n/1024, 5), b256, 0, stream>>>(hidden, wq, wk, wv, wo,
                                                x8, wq8, wk8, wv8, wo8, n);

  gemm_qkv<<<dim3(16, 16, 3), dim3(128), 0, stream>>>(x8, wq8, bq, bk, bv, q8);

  rope_qk<<<(S*NH*16)/256, b256, 0, stream>>>(q8, k8, cosp, sinp);
  vtrans<<<dim3(S/128, NH), b256, 0, stream>>>(v8, vt8);

  attn_stats<<<dim3(272, 16), b256, 0, stream>>>(q8, k8, stats);
  attn_reduce<<<dim3(16, 16), dim3(128), 0, stream>>>(stats, mlb);
  attn_score<<<dim3(272, 16), b256, 0, stream>>>(q8, k8, mlb, P8);
  attn_pv<<<dim3(16, 16, 2), b256, 0, stream>>>(P8, vt8, o8);

  gemm_o<<<dim3(16, 32), b256, 0, stream>>>(o8, wo8, bo, out);
}

// Round 13
// 154.660 us; speedup vs baseline: 1.0289x; 1.0289x over previous
//
#include <hip/hip_runtime.h>
#include <math.h>

typedef __attribute__((ext_vector_type(4))) int i32x4;
typedef signed char s8;

constexpr int S   = 2048;
constexpr int HID = 2048;
constexpr int NH  = 16;
constexpr int HD  = 128;
constexpr int HALF = 64;

#define SCORE_SCALE ((float)(0.06 * 0.06 * 0.08838834764831845))   // Q_ROT*K_ROT*INV_SQRT_HD
#define OSCALE      ((float)(((1.0 / 127.0) * 0.04) / 0.03))        // PROB*V_OUT/OUT_IN

__device__ __forceinline__ float clip127(float r){
  return fminf(fmaxf(r, -127.0f), 127.0f);
}
__device__ __forceinline__ i32x4 mfma_i8(i32x4 a, i32x4 b, i32x4 c){
  return __builtin_amdgcn_mfma_i32_16x16x64_i8(a, b, c, 0, 0, 0);
}
// async 16B global -> LDS (direct-to-LDS DMA, no VGPR round trip)
__device__ __forceinline__ void async16(const void* g, void* l){
  __builtin_amdgcn_global_load_lds(
      (const __attribute__((address_space(1))) unsigned*)g,
      (__attribute__((address_space(3))) unsigned*)l, 16, 0, 0);
}
// Stage ROWSx128 int8 tile: linear LDS dest (lane-ordered), inverse-swizzled
// global source, so swizzled reads (rd16) return the right data. [m173 pattern]
template<int ROWS>
__device__ __forceinline__ void stage_async_swz(s8* dst, const s8* src, int stride){
  const int tid = threadIdx.x;
#pragma unroll
  for (int i = 0; i < ROWS/32; ++i){
    int o = i*256 + tid;                 // 16B-chunk index
    int row = o >> 3, ch = o & 7;
    async16(src + (size_t)row*stride + ((ch ^ (row & 7))*16), dst + o*16);
  }
}
__device__ __forceinline__ i32x4 rd16(const s8* buf, int row, int ch){
  return *(const i32x4*)(buf + row*128 + ((ch ^ (row & 7))*16));
}
// decode triangular index t -> qt (t = qt*(qt+1)/2 + kt)
__device__ __forceinline__ int tri_qt(int t){
  int qt = (int)((sqrtf(8.f*t + 1.f) - 1.f)*0.5f);
  while ((qt+1)*(qt+2)/2 <= t) ++qt;
  while (qt*(qt+1)/2 > t) --qt;
  return qt;
}

// ---------------- prep: one dispatch converts x (quant) + 4 weights -> int8 ----
__global__ void cvt_all(const float* __restrict__ hid, const float* __restrict__ wq,
                        const float* __restrict__ wk, const float* __restrict__ wv,
                        const float* __restrict__ wo, s8* __restrict__ xd,
                        s8* __restrict__ qd, s8* __restrict__ kd,
                        s8* __restrict__ vd, s8* __restrict__ od, int n){
  const float* srcs[5] = {hid, wq, wk, wv, wo};
  s8* dsts[5] = {xd, qd, kd, vd, od};
  int which = blockIdx.y;
  const float* src = srcs[which];
  s8* dst = dsts[which];
  int i = (blockIdx.x * blockDim.x + threadIdx.x) * 4;
  if (i >= n) return;
  float4 v = *(const float4*)(src + i);
  float x[4] = {v.x, v.y, v.z, v.w};
  unsigned packed = 0;
#pragma unroll
  for (int j = 0; j < 4; ++j){
    int b;
    if (which == 0) b = (int)clip127(rintf(x[j] / 0.02f));
    else            b = (int)x[j];
    packed |= ((unsigned)(b & 255)) << (8*j);
  }
  *(unsigned*)(dst + i) = packed;
}

// ---------------- fused QKV GEMM: 128x128 tile, async-staged LDS ---------------
// grid (16,16,3): z selects {wq,wk,wv} and {q8,k8,v8}. Measured 58us structure.
// XCD swizzle (T1): per z, each XCD owns 2 bn-columns x 16 bm -> B panels
// become L2-resident (working set A 4.2MB + B 0.5MB vs 4MB L2). Bijective.
__global__ __launch_bounds__(256)
void gemm_qkv(const s8* __restrict__ A, const s8* __restrict__ W,
              const float* __restrict__ bq, const float* __restrict__ bk,
              const float* __restrict__ bv, s8* __restrict__ Out){
#pragma clang fp contract(off)
  constexpr int Kd = 2048, N = 2048;
  const int z = blockIdx.z;
  const s8* Bt = W + (size_t)z*(4u<<20);
  s8* Y = Out + (size_t)z*(4u<<20);
  const float* bss[3] = {bq, bk, bv};
  const float* bias = bss[z];
  __shared__ __attribute__((aligned(16))) s8 As[128*128];
  __shared__ __attribute__((aligned(16))) s8 Bs[128*128];
  const int lin = blockIdx.x + (blockIdx.y << 4);
  const int virt = (lin & 7)*32 + (lin >> 3);     // XCD-contiguous remap (256=8*32)
  const int bm = virt & 15, bn = virt >> 4;
  const int tid = threadIdx.x;
  const int wid = tid >> 6, lane = tid & 63;
  const int wm = wid >> 1, wn = wid & 1;
  const int col16 = lane & 15, g = lane >> 4;
  i32x4 acc[4][4] = {};
  const s8* Ab = A + (size_t)(bm*128)*Kd;
  const s8* Bb = Bt + (size_t)(bn*128)*Kd;
  for (int kt = 0; kt < 16; ++kt){
    stage_async_swz<128>(As, Ab + kt*128, Kd);
    stage_async_swz<128>(Bs, Bb + kt*128, Kd);
    __syncthreads();                       // drains vmcnt -> LDS ready
#pragma unroll
    for (int kk = 0; kk < 2; ++kk){
      i32x4 af[4], bf[4];
#pragma unroll
      for (int i = 0; i < 4; ++i) af[i] = rd16(As, wm*64 + i*16 + col16, kk*4 + g);
#pragma unroll
      for (int j = 0; j < 4; ++j) bf[j] = rd16(Bs, wn*64 + j*16 + col16, kk*4 + g);
#pragma unroll
      for (int i = 0; i < 4; ++i)
#pragma unroll
        for (int j = 0; j < 4; ++j)
          acc[i][j] = mfma_i8(af[i], bf[j], acc[i][j]);
    }
    __syncthreads();                       // all reads retired before restage
  }
#pragma unroll
  for (int i = 0; i < 4; ++i){
#pragma unroll
    for (int j = 0; j < 4; ++j){
      int row0 = bm*128 + wm*64 + i*16 + g*4;
      int col  = bn*128 + wn*64 + j*16 + col16;
#pragma unroll
      for (int r = 0; r < 4; ++r){
        float t = (float)acc[i][j][r] * 0.002f;
        t = t + bias[col];
        Y[(size_t)(row0 + r)*N + col] = (s8)(int)clip127(rintf(t));
      }
    }
  }
}

// ---------------- O-projection GEMM: 128x64 tile, single-buffer + XCD swizzle --
__global__ __launch_bounds__(256)
void gemm_o(const s8* __restrict__ A, const s8* __restrict__ Bt,
            const float* __restrict__ bias, float* __restrict__ Y){
#pragma clang fp contract(off)
  constexpr int Kd = 2048, N = 2048;
  __shared__ __attribute__((aligned(16))) s8 As[128*128];
  __shared__ __attribute__((aligned(16))) s8 Bs[64*128];
  const int lin = blockIdx.x + (blockIdx.y << 4);
  const int virt = (lin & 7)*64 + (lin >> 3);     // bijective (512=8*64)
  const int bm = virt & 15, bn = virt >> 4;       // bn in [0,32)
  const int tid = threadIdx.x;
  const int wid = tid >> 6, lane = tid & 63;
  const int wm = wid >> 1, wn = wid & 1;     // 2x2 waves -> 64x32 subtiles
  const int col16 = lane & 15, g = lane >> 4;
  i32x4 acc[4][2] = {};
  const s8* Ab = A + (size_t)(bm*128)*Kd;
  const s8* Bb = Bt + (size_t)(bn*64)*Kd;
  for (int kt = 0; kt < 16; ++kt){
    stage_async_swz<128>(As, Ab + kt*128, Kd);
    stage_async_swz<64>(Bs, Bb + kt*128, Kd);
    __syncthreads();
#pragma unroll
    for (int kk = 0; kk < 2; ++kk){
      i32x4 af[4], bf[2];
#pragma unroll
      for (int i = 0; i < 4; ++i) af[i] = rd16(As, wm*64 + i*16 + col16, kk*4 + g);
#pragma unroll
      for (int j = 0; j < 2; ++j) bf[j] = rd16(Bs, wn*32 + j*16 + col16, kk*4 + g);
#pragma unroll
      for (int i = 0; i < 4; ++i)
#pragma unroll
        for (int j = 0; j < 2; ++j)
          acc[i][j] = mfma_i8(af[i], bf[j], acc[i][j]);
    }
    __syncthreads();
  }
#pragma unroll
  for (int i = 0; i < 4; ++i){
#pragma unroll
    for (int j = 0; j < 2; ++j){
      int row0 = bm*128 + wm*64 + i*16 + g*4;
      int col  = bn*64 + wn*32 + j*16 + col16;
#pragma unroll
      for (int r = 0; r < 4; ++r){
        float t = (float)acc[i][j][r] * 0.001f;
        t = t + bias[col];
        Y[(size_t)(row0 + r)*N + col] = t;
      }
    }
  }
}

// ---------------- RoPE (in place on int8 q/k) ----------------------------------
__global__ void rope_qk(s8* __restrict__ q, s8* __restrict__ k,
                        const float* __restrict__ cosp, const float* __restrict__ sinp){
#pragma clang fp contract(off)
  int idx = blockIdx.x * blockDim.x + threadIdx.x;   // S*NH*16 threads
  int t4 = (idx & 15) * 4;
  int h  = (idx >> 4) & (NH-1);
  int s  = idx >> 8;
  if (s >= S) return;
  float4 c4 = *(const float4*)(cosp + s*HALF + t4);
  float4 s4 = *(const float4*)(sinp + s*HALF + t4);
  float cc[4] = {c4.x, c4.y, c4.z, c4.w}, ss[4] = {s4.x, s4.y, s4.z, s4.w};
  int base = s*HID + h*HD + t4;
  {
    int a0 = *(const int*)(q + base), a1 = *(const int*)(q + base + HALF);
    unsigned o0 = 0, o1 = 0;
#pragma unroll
    for (int j = 0; j < 4; ++j){
      float x0 = (float)((s8)(a0 >> (8*j))) * 0.05f;
      float x1 = (float)((s8)(a1 >> (8*j))) * 0.05f;
      float r0 = x0*cc[j] - x1*ss[j];
      float r1 = x0*ss[j] + x1*cc[j];
      o0 |= ((unsigned)(((int)clip127(rintf(r0 / 0.06f))) & 255)) << (8*j);
      o1 |= ((unsigned)(((int)clip127(rintf(r1 / 0.06f))) & 255)) << (8*j);
    }
    *(unsigned*)(q + base) = o0; *(unsigned*)(q + base + HALF) = o1;
  }
  {
    int a0 = *(const int*)(k + base), a1 = *(const int*)(k + base + HALF);
    unsigned o0 = 0, o1 = 0;
#pragma unroll
    for (int j = 0; j < 4; ++j){
      float x0 = (float)((s8)(a0 >> (8*j))) * 0.05f;
      float x1 = (float)((s8)(a1 >> (8*j))) * 0.05f;
      float r0 = x0*cc[j] - x1*ss[j];
      float r1 = x0*ss[j] + x1*cc[j];
      o0 |= ((unsigned)(((int)clip127(rintf(r0 / 0.06f))) & 255)) << (8*j);
      o1 |= ((unsigned)(((int)clip127(rintf(r1 / 0.06f))) & 255)) << (8*j);
    }
    *(unsigned*)(k + base) = o0; *(unsigned*)(k + base + HALF) = o1;
  }
}

// ---------------- V transpose (int8): vt[h][d][s] = v[s][h*HD+d] ---------------
__global__ void vtrans(const s8* __restrict__ v, s8* __restrict__ vt){
  __shared__ __attribute__((aligned(16))) s8 t[128*144];
  int s0 = blockIdx.x * 128, h = blockIdx.y;
  int tid = threadIdx.x;
#pragma unroll
  for (int i = 0; i < 4; ++i){
    int vv = i*256 + tid, r = vv >> 3, ch = vv & 7;
    *(i32x4*)(t + r*144 + ch*16) = *(const i32x4*)(v + (size_t)(s0 + r)*HID + h*HD + ch*16);
  }
  __syncthreads();
#pragma unroll
  for (int i = 0; i < 4; ++i){
    int vv = i*256 + tid, d = vv >> 3, sc = (vv & 7)*16;
    s8 tmp[16];
#pragma unroll
    for (int j = 0; j < 16; ++j) tmp[j] = t[(sc + j)*144 + d];
    *(i32x4*)(vt + (size_t)(h*HD + d)*S + s0 + sc) = *(i32x4*)tmp;
  }
}

// ---------------- S: tile stats at 64-row half-tile granularity ----------------
// grid (272,16): x -> (tri = x>>1, half = x&1). i32-domain max (bit-exact).
__global__ __launch_bounds__(256)
void attn_stats(const s8* __restrict__ qr, const s8* __restrict__ kr,
                float2* __restrict__ stats){
  const int x = blockIdx.x, h = blockIdx.y;
  const int tri = x >> 1, half = x & 1;
  const int qt = tri_qt(tri);
  const int kt = tri - qt*(qt+1)/2;
  const int q0 = qt*128 + half*64;
  const int tid = threadIdx.x, wid = tid >> 6, lane = tid & 63;
  const int col16 = lane & 15, g = lane >> 4;
  __shared__ __attribute__((aligned(16))) s8 Ks[128*128];

  stage_async_swz<128>(Ks, kr + (size_t)(kt*128)*HID + h*HD, HID);
  const s8* qb = qr + (size_t)(q0 + wid*16 + col16)*HID + h*HD + g*16;
  i32x4 aq[2];
  aq[0] = *(const i32x4*)(qb);
  aq[1] = *(const i32x4*)(qb + 64);
  __syncthreads();

  i32x4 sc[8] = {};
#pragma unroll
  for (int kk = 0; kk < 2; ++kk){
#pragma unroll
    for (int j = 0; j < 8; ++j){
      i32x4 bk = rd16(Ks, j*16 + col16, kk*4 + g);
      sc[j] = mfma_i8(aq[kk], bk, sc[j]);
    }
  }

  const bool diag = (kt == qt);
#pragma unroll
  for (int r = 0; r < 4; ++r){
    int rit = half*64 + wid*16 + g*4 + r;
    int qrow = qt*128 + rit;
    int mi = (int)0x80000000;
#pragma unroll
    for (int j = 0; j < 8; ++j){
      int v = sc[j][r];
      if (diag && (kt*128 + j*16 + col16 > qrow)) v = (int)0x80000000;
      mi = max(mi, v);
    }
    mi = max(mi, __shfl_xor(mi, 1));
    mi = max(mi, __shfl_xor(mi, 2));
    mi = max(mi, __shfl_xor(mi, 4));
    mi = max(mi, __shfl_xor(mi, 8));
    float mf = (float)mi * SCORE_SCALE;    // == f32 max (monotone map, exact cvt)
    float st = 0.f;
#pragma unroll
    for (int j = 0; j < 8; ++j){
      float arg;
      if (diag && (kt*128 + j*16 + col16 > qrow)) arg = -1e30f;  // exp -> 0.0f
      else arg = (float)sc[j][r] * SCORE_SCALE - mf;
      st += __expf(arg);
    }
    st += __shfl_xor(st, 1);
    st += __shfl_xor(st, 2);
    st += __shfl_xor(st, 4);
    st += __shfl_xor(st, 8);
    if (col16 == 0) stats[(size_t)(h*136 + tri)*128 + rit] = make_float2(mf, st);
  }
}

// ---------------- R: combine tile stats -> final (m, l) per row ----------------
__global__ void attn_reduce(const float2* __restrict__ stats, float2* __restrict__ ml){
  const int row = threadIdx.x, qt = blockIdx.x, h = blockIdx.y;
  const int tri = qt*(qt+1)/2;
  float m = -3.0e38f;
  for (int kt = 0; kt <= qt; ++kt)
    m = fmaxf(m, stats[(size_t)(h*136 + tri + kt)*128 + row].x);
  float l = 0.f;
  for (int kt = 0; kt <= qt; ++kt){
    float2 s = stats[(size_t)(h*136 + tri + kt)*128 + row];
    l += s.y * __expf(s.x - m);
  }
  ml[(h*16 + qt)*128 + row] = make_float2(m, l);
}

// ---------------- Q: p8 half-tile -> global P8 (j-serial, low VGPR) ------------
__global__ __launch_bounds__(256)
void attn_score(const s8* __restrict__ qr, const s8* __restrict__ kr,
                const float2* __restrict__ ml, s8* __restrict__ P8){
  const int x = blockIdx.x, h = blockIdx.y;
  const int tri = x >> 1, half = x & 1;
  const int qt = tri_qt(tri);
  const int kt = tri - qt*(qt+1)/2;
  const int q0 = qt*128 + half*64;
  const int tid = threadIdx.x, wid = tid >> 6, lane = tid & 63;
  const int col16 = lane & 15, g = lane >> 4;
  __shared__ __attribute__((aligned(16))) s8 Ks[128*128];
  __shared__ __attribute__((aligned(16))) s8 Pl[64*128];

  stage_async_swz<128>(Ks, kr + (size_t)(kt*128)*HID + h*HD, HID);
  const s8* qb = qr + (size_t)(q0 + wid*16 + col16)*HID + h*HD + g*16;
  i32x4 aq[2];
  aq[0] = *(const i32x4*)(qb);
  aq[1] = *(const i32x4*)(qb + 64);
  float m[4], c[4];
#pragma unroll
  for (int r = 0; r < 4; ++r){
    float2 t = ml[(h*16 + qt)*128 + half*64 + wid*16 + g*4 + r];
    m[r] = t.x;
    c[r] = 127.0f / t.y;
  }
  __syncthreads();

  const bool diag = (kt == qt);
#pragma unroll
  for (int j = 0; j < 8; ++j){
    i32x4 s0 = {};
    s0 = mfma_i8(aq[0], rd16(Ks, j*16 + col16, g), s0);
    s0 = mfma_i8(aq[1], rd16(Ks, j*16 + col16, 4 + g), s0);
    int colk = j*16 + col16;
#pragma unroll
    for (int r = 0; r < 4; ++r){
      int row = wid*16 + g*4 + r;          // local row in [0,64)
      int qrow = q0 + row;
      float p8v = 0.0f;
      if (!diag || (kt*128 + colk) <= qrow){
        float sv = (float)s0[r] * SCORE_SCALE;
        p8v = clip127(rintf(__expf(sv - m[r]) * c[r]));
      }
      Pl[row*128 + colk] = (s8)(int)p8v;
    }
  }
  __syncthreads();
  s8* dst = P8 + (size_t)(h*136 + tri)*16384 + half*8192;
#pragma unroll
  for (int i = 0; i < 2; ++i){
    int o = i*256 + tid;
    *(i32x4*)(dst + o*16) = *(const i32x4*)(Pl + o*16);
  }
}

// ---------------- P: PV — LDS-staged (gemm-identical structure), d-half split --
// grid (16,16,2): x -> qt = 15-x (deepest blocks launch first), z = d-half.
// Per kt-tile: async-stage P(16KB)+V(8KB) -> barrier -> 16 MFMA/wave -> barrier.
__global__ __launch_bounds__(256)
void attn_pv(const s8* __restrict__ P8, const s8* __restrict__ vt8,
             s8* __restrict__ o8){
  const int qt = 15 - blockIdx.x;          // deepest first
  const int h = blockIdx.y, dh = blockIdx.z;
  const int tri = qt*(qt+1)/2;
  const int tid = threadIdx.x, wid = tid >> 6, lane = tid & 63;
  const int wm = wid >> 1, wn = wid & 1;   // 2x2 waves: 64 rows x 32 d each
  const int col16 = lane & 15, g = lane >> 4;
  __shared__ __attribute__((aligned(16))) s8 Ps[128*128];
  __shared__ __attribute__((aligned(16))) s8 Vs[64*128];

  i32x4 acc[4][2] = {};
  for (int kt = 0; kt <= qt; ++kt){
    stage_async_swz<128>(Ps, P8 + (size_t)(h*136 + tri + kt)*16384, 128);
    stage_async_swz<64>(Vs, vt8 + (size_t)(h*HD + dh*64)*S + kt*128, S);
    __syncthreads();                       // drains vmcnt -> LDS ready
#pragma unroll
    for (int kk = 0; kk < 2; ++kk){
      i32x4 af[4], bf[2];
#pragma unroll
      for (int i = 0; i < 4; ++i) af[i] = rd16(Ps, wm*64 + i*16 + col16, kk*4 + g);
#pragma unroll
      for (int j = 0; j < 2; ++j) bf[j] = rd16(Vs, wn*32 + j*16 + col16, kk*4 + g);
#pragma unroll
      for (int i = 0; i < 4; ++i)
#pragma unroll
        for (int j = 0; j < 2; ++j)
          acc[i][j] = mfma_i8(af[i], bf[j], acc[i][j]);
    }
    __syncthreads();                       // all reads retired before restage
  }
#pragma unroll
  for (int i = 0; i < 4; ++i)
#pragma unroll
    for (int j = 0; j < 2; ++j)
#pragma unroll
      for (int r = 0; r < 4; ++r){
        int row = qt*128 + wm*64 + i*16 + g*4 + r;
        int d = dh*64 + wn*32 + j*16 + col16;
        o8[(size_t)row*HID + h*HD + d] = (s8)(int)clip127(rintf((float)acc[i][j][r] * OSCALE));
      }
}

// ---------------- launch --------------------------------------------------------
extern "C" void kernel_launch(void* const* d_in, const int* in_sizes, int n_in,
                              void* d_out, int out_size, void* d_ws, size_t ws_size,
                              hipStream_t stream) {
  const float* hidden = (const float*)d_in[0];
  const float* cosp   = (const float*)d_in[1];
  const float* sinp   = (const float*)d_in[2];
  const float* wq     = (const float*)d_in[3];
  const float* wk     = (const float*)d_in[4];
  const float* wv     = (const float*)d_in[5];
  const float* wo     = (const float*)d_in[6];
  const float* bq     = (const float*)d_in[7];
  const float* bk     = (const float*)d_in[8];
  const float* bv     = (const float*)d_in[9];
  const float* bo     = (const float*)d_in[10];
  float* out = (float*)d_out;

  const size_t MB = 1024*1024;
  s8* ws8 = (s8*)d_ws;
  s8* x8  = ws8 + 0*MB;     // 4MB; reused as o8 (x8 dead after QKV GEMM)
  s8* wq8 = ws8 + 4*MB;     // {wq,wk,wv} contiguous for fused QKV GEMM
  s8* wk8 = ws8 + 8*MB;
  s8* wv8 = ws8 + 12*MB;
  s8* wo8 = ws8 + 16*MB;
  s8* q8  = ws8 + 20*MB;    // {q,k,v} contiguous (gemm_qkv writes via z offset)
  s8* k8  = ws8 + 24*MB;
  s8* v8  = ws8 + 28*MB;
  s8* vt8 = ws8 + 32*MB;    // v transposed per head
  s8* P8  = ws8 + 36*MB;    // 16*136*16384 = 35.65MB -> ends ~71.7MB
  s8* o8  = x8;
  float2* stats = (float2*)(ws8 + 4*MB);                 // overlays dead wq8
  float2* mlb   = (float2*)(ws8 + 4*MB + 2400*1024);

  const int n = HID*HID;
  dim3 b256(256);

  cvt_all<<<dim3(n/1024, 5), b256, 0, stream>>>(hidden, wq, wk, wv, wo,
                                                x8, wq8, wk8, wv8, wo8, n);

  gemm_qkv<<<dim3(16, 16, 3), b256, 0, stream>>>(x8, wq8, bq, bk, bv, q8);

  rope_qk<<<(S*NH*16)/256, b256, 0, stream>>>(q8, k8, cosp, sinp);
  vtrans<<<dim3(S/128, NH), b256, 0, stream>>>(v8, vt8);

  attn_stats<<<dim3(272, 16), b256, 0, stream>>>(q8, k8, stats);
  attn_reduce<<<dim3(16, 16), dim3(128), 0, stream>>>(stats, mlb);
  attn_score<<<dim3(272, 16), b256, 0, stream>>>(q8, k8, mlb, P8);
  attn_pv<<<dim3(16, 16, 2), b256, 0, stream>>>(P8, vt8, o8);

  gemm_o<<<dim3(16, 32), b256, 0, stream>>>(o8, wo8, bo, out);
}

// Round 14
// 144.353 us; speedup vs baseline: 1.1023x; 1.0714x over previous
//
#include <hip/hip_runtime.h>
#include <math.h>

typedef __attribute__((ext_vector_type(4))) int i32x4;
typedef signed char s8;

constexpr int S   = 2048;
constexpr int HID = 2048;
constexpr int NH  = 16;
constexpr int HD  = 128;
constexpr int HALF = 64;

#define SCORE_SCALE ((float)(0.06 * 0.06 * 0.08838834764831845))   // Q_ROT*K_ROT*INV_SQRT_HD
#define OSCALE      ((float)(((1.0 / 127.0) * 0.04) / 0.03))        // PROB*V_OUT/OUT_IN

__device__ __forceinline__ float clip127(float r){
  return fminf(fmaxf(r, -127.0f), 127.0f);
}
__device__ __forceinline__ i32x4 mfma_i8(i32x4 a, i32x4 b, i32x4 c){
  return __builtin_amdgcn_mfma_i32_16x16x64_i8(a, b, c, 0, 0, 0);
}
// async 16B global -> LDS (direct-to-LDS DMA, no VGPR round trip)
__device__ __forceinline__ void async16(const void* g, void* l){
  __builtin_amdgcn_global_load_lds(
      (const __attribute__((address_space(1))) unsigned*)g,
      (__attribute__((address_space(3))) unsigned*)l, 16, 0, 0);
}
// Stage ROWSx128 int8 tile: linear LDS dest (lane-ordered), inverse-swizzled
// global source, so swizzled reads (rd16) return the right data. [m173 pattern]
template<int ROWS>
__device__ __forceinline__ void stage_async_swz(s8* dst, const s8* src, int stride){
  const int tid = threadIdx.x;
#pragma unroll
  for (int i = 0; i < ROWS/32; ++i){
    int o = i*256 + tid;                 // 16B-chunk index
    int row = o >> 3, ch = o & 7;
    async16(src + (size_t)row*stride + ((ch ^ (row & 7))*16), dst + o*16);
  }
}
__device__ __forceinline__ i32x4 rd16(const s8* buf, int row, int ch){
  return *(const i32x4*)(buf + row*128 + ((ch ^ (row & 7))*16));
}
// 128x64 (BK=64) variants: 4 chunks/row; swizzle slot = ch ^ ((row>>2)&3)
// gives 2-way (free) bank pattern on 16-lane fragment reads.
__device__ __forceinline__ void stage64(s8* dst, const s8* src, int stride){
  const int tid = threadIdx.x;
#pragma unroll
  for (int i = 0; i < 2; ++i){
    int o = i*256 + tid;                 // 512 chunks = 128 rows x 64 B
    int row = o >> 2, slot = o & 3;
    int ch = slot ^ ((row >> 2) & 3);    // inverse swizzle on global source
    async16(src + (size_t)row*stride + ch*16, dst + o*16);
  }
}
__device__ __forceinline__ i32x4 rd64(const s8* buf, int row, int g){
  return *(const i32x4*)(buf + row*64 + ((g ^ ((row >> 2) & 3))*16));
}
// decode triangular index t -> qt (t = qt*(qt+1)/2 + kt)
__device__ __forceinline__ int tri_qt(int t){
  int qt = (int)((sqrtf(8.f*t + 1.f) - 1.f)*0.5f);
  while ((qt+1)*(qt+2)/2 <= t) ++qt;
  while (qt*(qt+1)/2 > t) --qt;
  return qt;
}

// ---------------- prep: one dispatch converts x (quant) + 4 weights -> int8 ----
__global__ void cvt_all(const float* __restrict__ hid, const float* __restrict__ wq,
                        const float* __restrict__ wk, const float* __restrict__ wv,
                        const float* __restrict__ wo, s8* __restrict__ xd,
                        s8* __restrict__ qd, s8* __restrict__ kd,
                        s8* __restrict__ vd, s8* __restrict__ od, int n){
  const float* srcs[5] = {hid, wq, wk, wv, wo};
  s8* dsts[5] = {xd, qd, kd, vd, od};
  int which = blockIdx.y;
  const float* src = srcs[which];
  s8* dst = dsts[which];
  int i = (blockIdx.x * blockDim.x + threadIdx.x) * 4;
  if (i >= n) return;
  float4 v = *(const float4*)(src + i);
  float x[4] = {v.x, v.y, v.z, v.w};
  unsigned packed = 0;
#pragma unroll
  for (int j = 0; j < 4; ++j){
    int b;
    if (which == 0) b = (int)clip127(rintf(x[j] / 0.02f));
    else            b = (int)x[j];
    packed |= ((unsigned)(b & 255)) << (8*j);
  }
  *(unsigned*)(dst + i) = packed;
}

// ---------------- fused QKV GEMM: 128x128 tile, counted-vmcnt pipeline ---------
// grid (16,16,3). BK=64, 3 LDS buffers (48KB), stage-ahead-2: iter T issues
// tile T+2's loads, computes tile T, then s_waitcnt vmcnt(4) (NOT 0) + raw
// s_barrier -> staging loads stay in flight across barriers (T4 mechanism).
// Safety: buf[(T+2)%3] was last read at iter T-1 (reads retired pre-barrier);
// each wave's own vmcnt(4) before the barrier publishes tile T+1's DMA writes.
__global__ __launch_bounds__(256)
void gemm_qkv(const s8* __restrict__ A, const s8* __restrict__ W,
              const float* __restrict__ bq, const float* __restrict__ bk,
              const float* __restrict__ bv, s8* __restrict__ Out){
#pragma clang fp contract(off)
  constexpr int Kd = 2048, N = 2048, NT = 32;
  const int z = blockIdx.z;
  const s8* Bt = W + (size_t)z*(4u<<20);
  s8* Y = Out + (size_t)z*(4u<<20);
  const float* bss[3] = {bq, bk, bv};
  const float* bias = bss[z];
  __shared__ __attribute__((aligned(16))) s8 As[3][128*64];
  __shared__ __attribute__((aligned(16))) s8 Bs[3][128*64];
  const int lin = blockIdx.x + (blockIdx.y << 4);
  const int virt = (lin & 7)*32 + (lin >> 3);     // XCD-contiguous remap
  const int bm = virt & 15, bn = virt >> 4;
  const int tid = threadIdx.x;
  const int wid = tid >> 6, lane = tid & 63;
  const int wm = wid >> 1, wn = wid & 1;
  const int col16 = lane & 15, g = lane >> 4;
  i32x4 acc[4][4] = {};
  const s8* Ab = A + (size_t)(bm*128)*Kd;
  const s8* Bb = Bt + (size_t)(bn*128)*Kd;

  stage64(As[0], Ab, Kd);       stage64(Bs[0], Bb, Kd);        // tile 0
  stage64(As[1], Ab + 64, Kd);  stage64(Bs[1], Bb + 64, Kd);   // tile 1
  asm volatile("s_waitcnt vmcnt(4)" ::: "memory");             // tile 0 ready
  __builtin_amdgcn_s_barrier();

  for (int T = 0; T < NT; ++T){
    const int nxt = T + 2;
    if (nxt < NT){
      stage64(As[nxt%3], Ab + nxt*64, Kd);   // 2 loads
      stage64(Bs[nxt%3], Bb + nxt*64, Kd);   // 2 loads
    }
    const s8* as = As[T%3];
    const s8* bs = Bs[T%3];
    i32x4 af[4], bf[4];
#pragma unroll
    for (int i = 0; i < 4; ++i) af[i] = rd64(as, wm*64 + i*16 + col16, g);
#pragma unroll
    for (int j = 0; j < 4; ++j) bf[j] = rd64(bs, wn*64 + j*16 + col16, g);
#pragma unroll
    for (int i = 0; i < 4; ++i)
#pragma unroll
      for (int j = 0; j < 4; ++j)
        acc[i][j] = mfma_i8(af[i], bf[j], acc[i][j]);
    if (nxt < NT) asm volatile("s_waitcnt vmcnt(4)" ::: "memory"); // T+1 ready, T+2 flying
    else          asm volatile("s_waitcnt vmcnt(0)" ::: "memory"); // tail drain
    __builtin_amdgcn_s_barrier();
  }

#pragma unroll
  for (int i = 0; i < 4; ++i){
#pragma unroll
    for (int j = 0; j < 4; ++j){
      int row0 = bm*128 + wm*64 + i*16 + g*4;
      int col  = bn*128 + wn*64 + j*16 + col16;
#pragma unroll
      for (int r = 0; r < 4; ++r){
        float t = (float)acc[i][j][r] * 0.002f;
        t = t + bias[col];
        Y[(size_t)(row0 + r)*N + col] = (s8)(int)clip127(rintf(t));
      }
    }
  }
}

// ---------------- O-projection GEMM: 128x64 tile, single-buffer + XCD swizzle --
__global__ __launch_bounds__(256)
void gemm_o(const s8* __restrict__ A, const s8* __restrict__ Bt,
            const float* __restrict__ bias, float* __restrict__ Y){
#pragma clang fp contract(off)
  constexpr int Kd = 2048, N = 2048;
  __shared__ __attribute__((aligned(16))) s8 As[128*128];
  __shared__ __attribute__((aligned(16))) s8 Bs[64*128];
  const int lin = blockIdx.x + (blockIdx.y << 4);
  const int virt = (lin & 7)*64 + (lin >> 3);     // bijective (512=8*64)
  const int bm = virt & 15, bn = virt >> 4;       // bn in [0,32)
  const int tid = threadIdx.x;
  const int wid = tid >> 6, lane = tid & 63;
  const int wm = wid >> 1, wn = wid & 1;     // 2x2 waves -> 64x32 subtiles
  const int col16 = lane & 15, g = lane >> 4;
  i32x4 acc[4][2] = {};
  const s8* Ab = A + (size_t)(bm*128)*Kd;
  const s8* Bb = Bt + (size_t)(bn*64)*Kd;
  for (int kt = 0; kt < 16; ++kt){
    stage_async_swz<128>(As, Ab + kt*128, Kd);
    stage_async_swz<64>(Bs, Bb + kt*128, Kd);
    __syncthreads();
#pragma unroll
    for (int kk = 0; kk < 2; ++kk){
      i32x4 af[4], bf[2];
#pragma unroll
      for (int i = 0; i < 4; ++i) af[i] = rd16(As, wm*64 + i*16 + col16, kk*4 + g);
#pragma unroll
      for (int j = 0; j < 2; ++j) bf[j] = rd16(Bs, wn*32 + j*16 + col16, kk*4 + g);
#pragma unroll
      for (int i = 0; i < 4; ++i)
#pragma unroll
        for (int j = 0; j < 2; ++j)
          acc[i][j] = mfma_i8(af[i], bf[j], acc[i][j]);
    }
    __syncthreads();
  }
#pragma unroll
  for (int i = 0; i < 4; ++i){
#pragma unroll
    for (int j = 0; j < 2; ++j){
      int row0 = bm*128 + wm*64 + i*16 + g*4;
      int col  = bn*64 + wn*32 + j*16 + col16;
#pragma unroll
      for (int r = 0; r < 4; ++r){
        float t = (float)acc[i][j][r] * 0.001f;
        t = t + bias[col];
        Y[(size_t)(row0 + r)*N + col] = t;
      }
    }
  }
}

// ---------------- RoPE (in place on int8 q/k) ----------------------------------
__global__ void rope_qk(s8* __restrict__ q, s8* __restrict__ k,
                        const float* __restrict__ cosp, const float* __restrict__ sinp){
#pragma clang fp contract(off)
  int idx = blockIdx.x * blockDim.x + threadIdx.x;   // S*NH*16 threads
  int t4 = (idx & 15) * 4;
  int h  = (idx >> 4) & (NH-1);
  int s  = idx >> 8;
  if (s >= S) return;
  float4 c4 = *(const float4*)(cosp + s*HALF + t4);
  float4 s4 = *(const float4*)(sinp + s*HALF + t4);
  float cc[4] = {c4.x, c4.y, c4.z, c4.w}, ss[4] = {s4.x, s4.y, s4.z, s4.w};
  int base = s*HID + h*HD + t4;
  {
    int a0 = *(const int*)(q + base), a1 = *(const int*)(q + base + HALF);
    unsigned o0 = 0, o1 = 0;
#pragma unroll
    for (int j = 0; j < 4; ++j){
      float x0 = (float)((s8)(a0 >> (8*j))) * 0.05f;
      float x1 = (float)((s8)(a1 >> (8*j))) * 0.05f;
      float r0 = x0*cc[j] - x1*ss[j];
      float r1 = x0*ss[j] + x1*cc[j];
      o0 |= ((unsigned)(((int)clip127(rintf(r0 / 0.06f))) & 255)) << (8*j);
      o1 |= ((unsigned)(((int)clip127(rintf(r1 / 0.06f))) & 255)) << (8*j);
    }
    *(unsigned*)(q + base) = o0; *(unsigned*)(q + base + HALF) = o1;
  }
  {
    int a0 = *(const int*)(k + base), a1 = *(const int*)(k + base + HALF);
    unsigned o0 = 0, o1 = 0;
#pragma unroll
    for (int j = 0; j < 4; ++j){
      float x0 = (float)((s8)(a0 >> (8*j))) * 0.05f;
      float x1 = (float)((s8)(a1 >> (8*j))) * 0.05f;
      float r0 = x0*cc[j] - x1*ss[j];
      float r1 = x0*ss[j] + x1*cc[j];
      o0 |= ((unsigned)(((int)clip127(rintf(r0 / 0.06f))) & 255)) << (8*j);
      o1 |= ((unsigned)(((int)clip127(rintf(r1 / 0.06f))) & 255)) << (8*j);
    }
    *(unsigned*)(k + base) = o0; *(unsigned*)(k + base + HALF) = o1;
  }
}

// ---------------- V transpose (int8): vt[h][d][s] = v[s][h*HD+d] ---------------
__global__ void vtrans(const s8* __restrict__ v, s8* __restrict__ vt){
  __shared__ __attribute__((aligned(16))) s8 t[128*144];
  int s0 = blockIdx.x * 128, h = blockIdx.y;
  int tid = threadIdx.x;
#pragma unroll
  for (int i = 0; i < 4; ++i){
    int vv = i*256 + tid, r = vv >> 3, ch = vv & 7;
    *(i32x4*)(t + r*144 + ch*16) = *(const i32x4*)(v + (size_t)(s0 + r)*HID + h*HD + ch*16);
  }
  __syncthreads();
#pragma unroll
  for (int i = 0; i < 4; ++i){
    int vv = i*256 + tid, d = vv >> 3, sc = (vv & 7)*16;
    s8 tmp[16];
#pragma unroll
    for (int j = 0; j < 16; ++j) tmp[j] = t[(sc + j)*144 + d];
    *(i32x4*)(vt + (size_t)(h*HD + d)*S + s0 + sc) = *(i32x4*)tmp;
  }
}

// ---------------- S: tile stats at 64-row half-tile granularity ----------------
__global__ __launch_bounds__(256)
void attn_stats(const s8* __restrict__ qr, const s8* __restrict__ kr,
                float2* __restrict__ stats){
  const int x = blockIdx.x, h = blockIdx.y;
  const int tri = x >> 1, half = x & 1;
  const int qt = tri_qt(tri);
  const int kt = tri - qt*(qt+1)/2;
  const int q0 = qt*128 + half*64;
  const int tid = threadIdx.x, wid = tid >> 6, lane = tid & 63;
  const int col16 = lane & 15, g = lane >> 4;
  __shared__ __attribute__((aligned(16))) s8 Ks[128*128];

  stage_async_swz<128>(Ks, kr + (size_t)(kt*128)*HID + h*HD, HID);
  const s8* qb = qr + (size_t)(q0 + wid*16 + col16)*HID + h*HD + g*16;
  i32x4 aq[2];
  aq[0] = *(const i32x4*)(qb);
  aq[1] = *(const i32x4*)(qb + 64);
  __syncthreads();

  i32x4 sc[8] = {};
#pragma unroll
  for (int kk = 0; kk < 2; ++kk){
#pragma unroll
    for (int j = 0; j < 8; ++j){
      i32x4 bk = rd16(Ks, j*16 + col16, kk*4 + g);
      sc[j] = mfma_i8(aq[kk], bk, sc[j]);
    }
  }

  const bool diag = (kt == qt);
#pragma unroll
  for (int r = 0; r < 4; ++r){
    int rit = half*64 + wid*16 + g*4 + r;
    int qrow = qt*128 + rit;
    int mi = (int)0x80000000;
#pragma unroll
    for (int j = 0; j < 8; ++j){
      int v = sc[j][r];
      if (diag && (kt*128 + j*16 + col16 > qrow)) v = (int)0x80000000;
      mi = max(mi, v);
    }
    mi = max(mi, __shfl_xor(mi, 1));
    mi = max(mi, __shfl_xor(mi, 2));
    mi = max(mi, __shfl_xor(mi, 4));
    mi = max(mi, __shfl_xor(mi, 8));
    float mf = (float)mi * SCORE_SCALE;    // == f32 max (monotone map, exact cvt)
    float st = 0.f;
#pragma unroll
    for (int j = 0; j < 8; ++j){
      float arg;
      if (diag && (kt*128 + j*16 + col16 > qrow)) arg = -1e30f;  // exp -> 0.0f
      else arg = (float)sc[j][r] * SCORE_SCALE - mf;
      st += __expf(arg);
    }
    st += __shfl_xor(st, 1);
    st += __shfl_xor(st, 2);
    st += __shfl_xor(st, 4);
    st += __shfl_xor(st, 8);
    if (col16 == 0) stats[(size_t)(h*136 + tri)*128 + rit] = make_float2(mf, st);
  }
}

// ---------------- R: combine tile stats -> final (m, l) per row ----------------
__global__ void attn_reduce(const float2* __restrict__ stats, float2* __restrict__ ml){
  const int row = threadIdx.x, qt = blockIdx.x, h = blockIdx.y;
  const int tri = qt*(qt+1)/2;
  float m = -3.0e38f;
  for (int kt = 0; kt <= qt; ++kt)
    m = fmaxf(m, stats[(size_t)(h*136 + tri + kt)*128 + row].x);
  float l = 0.f;
  for (int kt = 0; kt <= qt; ++kt){
    float2 s = stats[(size_t)(h*136 + tri + kt)*128 + row];
    l += s.y * __expf(s.x - m);
  }
  ml[(h*16 + qt)*128 + row] = make_float2(m, l);
}

// ---------------- Q: p8 half-tile -> global P8 (j-serial, low VGPR) ------------
__global__ __launch_bounds__(256)
void attn_score(const s8* __restrict__ qr, const s8* __restrict__ kr,
                const float2* __restrict__ ml, s8* __restrict__ P8){
  const int x = blockIdx.x, h = blockIdx.y;
  const int tri = x >> 1, half = x & 1;
  const int qt = tri_qt(tri);
  const int kt = tri - qt*(qt+1)/2;
  const int q0 = qt*128 + half*64;
  const int tid = threadIdx.x, wid = tid >> 6, lane = tid & 63;
  const int col16 = lane & 15, g = lane >> 4;
  __shared__ __attribute__((aligned(16))) s8 Ks[128*128];
  __shared__ __attribute__((aligned(16))) s8 Pl[64*128];

  stage_async_swz<128>(Ks, kr + (size_t)(kt*128)*HID + h*HD, HID);
  const s8* qb = qr + (size_t)(q0 + wid*16 + col16)*HID + h*HD + g*16;
  i32x4 aq[2];
  aq[0] = *(const i32x4*)(qb);
  aq[1] = *(const i32x4*)(qb + 64);
  float m[4], c[4];
#pragma unroll
  for (int r = 0; r < 4; ++r){
    float2 t = ml[(h*16 + qt)*128 + half*64 + wid*16 + g*4 + r];
    m[r] = t.x;
    c[r] = 127.0f / t.y;
  }
  __syncthreads();

  const bool diag = (kt == qt);
#pragma unroll
  for (int j = 0; j < 8; ++j){
    i32x4 s0 = {};
    s0 = mfma_i8(aq[0], rd16(Ks, j*16 + col16, g), s0);
    s0 = mfma_i8(aq[1], rd16(Ks, j*16 + col16, 4 + g), s0);
    int colk = j*16 + col16;
#pragma unroll
    for (int r = 0; r < 4; ++r){
      int row = wid*16 + g*4 + r;          // local row in [0,64)
      int qrow = q0 + row;
      float p8v = 0.0f;
      if (!diag || (kt*128 + colk) <= qrow){
        float sv = (float)s0[r] * SCORE_SCALE;
        p8v = clip127(rintf(__expf(sv - m[r]) * c[r]));
      }
      Pl[row*128 + colk] = (s8)(int)p8v;
    }
  }
  __syncthreads();
  s8* dst = P8 + (size_t)(h*136 + tri)*16384 + half*8192;
#pragma unroll
  for (int i = 0; i < 2; ++i){
    int o = i*256 + tid;
    *(i32x4*)(dst + o*16) = *(const i32x4*)(Pl + o*16);
  }
}

// ---------------- P: PV — LDS-staged (gemm-identical structure), d-half split --
__global__ __launch_bounds__(256)
void attn_pv(const s8* __restrict__ P8, const s8* __restrict__ vt8,
             s8* __restrict__ o8){
  const int qt = 15 - blockIdx.x;          // deepest first
  const int h = blockIdx.y, dh = blockIdx.z;
  const int tri = qt*(qt+1)/2;
  const int tid = threadIdx.x, wid = tid >> 6, lane = tid & 63;
  const int wm = wid >> 1, wn = wid & 1;   // 2x2 waves: 64 rows x 32 d each
  const int col16 = lane & 15, g = lane >> 4;
  __shared__ __attribute__((aligned(16))) s8 Ps[128*128];
  __shared__ __attribute__((aligned(16))) s8 Vs[64*128];

  i32x4 acc[4][2] = {};
  for (int kt = 0; kt <= qt; ++kt){
    stage_async_swz<128>(Ps, P8 + (size_t)(h*136 + tri + kt)*16384, 128);
    stage_async_swz<64>(Vs, vt8 + (size_t)(h*HD + dh*64)*S + kt*128, S);
    __syncthreads();                       // drains vmcnt -> LDS ready
#pragma unroll
    for (int kk = 0; kk < 2; ++kk){
      i32x4 af[4], bf[2];
#pragma unroll
      for (int i = 0; i < 4; ++i) af[i] = rd16(Ps, wm*64 + i*16 + col16, kk*4 + g);
#pragma unroll
      for (int j = 0; j < 2; ++j) bf[j] = rd16(Vs, wn*32 + j*16 + col16, kk*4 + g);
#pragma unroll
      for (int i = 0; i < 4; ++i)
#pragma unroll
        for (int j = 0; j < 2; ++j)
          acc[i][j] = mfma_i8(af[i], bf[j], acc[i][j]);
    }
    __syncthreads();                       // all reads retired before restage
  }
#pragma unroll
  for (int i = 0; i < 4; ++i)
#pragma unroll
    for (int j = 0; j < 2; ++j)
#pragma unroll
      for (int r = 0; r < 4; ++r){
        int row = qt*128 + wm*64 + i*16 + g*4 + r;
        int d = dh*64 + wn*32 + j*16 + col16;
        o8[(size_t)row*HID + h*HD + d] = (s8)(int)clip127(rintf((float)acc[i][j][r] * OSCALE));
      }
}

// ---------------- launch --------------------------------------------------------
extern "C" void kernel_launch(void* const* d_in, const int* in_sizes, int n_in,
                              void* d_out, int out_size, void* d_ws, size_t ws_size,
                              hipStream_t stream) {
  const float* hidden = (const float*)d_in[0];
  const float* cosp   = (const float*)d_in[1];
  const float* sinp   = (const float*)d_in[2];
  const float* wq     = (const float*)d_in[3];
  const float* wk     = (const float*)d_in[4];
  const float* wv     = (const float*)d_in[5];
  const float* wo     = (const float*)d_in[6];
  const float* bq     = (const float*)d_in[7];
  const float* bk     = (const float*)d_in[8];
  const float* bv     = (const float*)d_in[9];
  const float* bo     = (const float*)d_in[10];
  float* out = (float*)d_out;

  const size_t MB = 1024*1024;
  s8* ws8 = (s8*)d_ws;
  s8* x8  = ws8 + 0*MB;     // 4MB; reused as o8 (x8 dead after QKV GEMM)
  s8* wq8 = ws8 + 4*MB;     // {wq,wk,wv} contiguous for fused QKV GEMM
  s8* wk8 = ws8 + 8*MB;
  s8* wv8 = ws8 + 12*MB;
  s8* wo8 = ws8 + 16*MB;
  s8* q8  = ws8 + 20*MB;    // {q,k,v} contiguous (gemm_qkv writes via z offset)
  s8* k8  = ws8 + 24*MB;
  s8* v8  = ws8 + 28*MB;
  s8* vt8 = ws8 + 32*MB;    // v transposed per head
  s8* P8  = ws8 + 36*MB;    // 16*136*16384 = 35.65MB -> ends ~71.7MB
  s8* o8  = x8;
  float2* stats = (float2*)(ws8 + 4*MB);                 // overlays dead wq8
  float2* mlb   = (float2*)(ws8 + 4*MB + 2400*1024);

  const int n = HID*HID;
  dim3 b256(256);

  cvt_all<<<dim3(n/1024, 5), b256, 0, stream>>>(hidden, wq, wk, wv, wo,
                                                x8, wq8, wk8, wv8, wo8, n);

  gemm_qkv<<<dim3(16, 16, 3), b256, 0, stream>>>(x8, wq8, bq, bk, bv, q8);

  rope_qk<<<(S*NH*16)/256, b256, 0, stream>>>(q8, k8, cosp, sinp);
  vtrans<<<dim3(S/128, NH), b256, 0, stream>>>(v8, vt8);

  attn_stats<<<dim3(272, 16), b256, 0, stream>>>(q8, k8, stats);
  attn_reduce<<<dim3(16, 16), dim3(128), 0, stream>>>(stats, mlb);
  attn_score<<<dim3(272, 16), b256, 0, stream>>>(q8, k8, mlb, P8);
  attn_pv<<<dim3(16, 16, 2), b256, 0, stream>>>(P8, vt8, o8);

  gemm_o<<<dim3(16, 32), b256, 0, stream>>>(o8, wo8, bo, out);
}